// Round 20
// baseline (123.684 us; speedup 1.0000x reference)
//
#include <hip/hip_runtime.h>
#include <hip/hip_bf16.h>
#include <stdint.h>

typedef __bf16 bf16_t;
typedef __bf16 bf16x4 __attribute__((ext_vector_type(4)));
typedef __bf16 bf16x8 __attribute__((ext_vector_type(8)));
typedef float  f32x4  __attribute__((ext_vector_type(4)));

#define DM    1024
#define NH    16
#define HD    64
#define SEQ   2048
#define BATCH 2
#define BS    (BATCH*SEQ)   // 4096
#define NQKV  (3*DM)        // 3072

#define GLOAD_LDS16(g, l) \
  __builtin_amdgcn_global_load_lds((const __attribute__((address_space(1))) void*)(g), \
                                   (__attribute__((address_space(3))) void*)(l), 16, 0, 0)

__device__ __forceinline__ f32x4 mfma16(bf16x8 a, bf16x8 b, f32x4 c) {
  return __builtin_amdgcn_mfma_f32_16x16x32_bf16(a, b, c, 0, 0, 0);
}

// ---------------- merged cast/copy + rope-table kernel ----------------
__global__ __launch_bounds__(256) void k_cast_all(
    const float* __restrict__ x,  const float* __restrict__ Wq,
    const float* __restrict__ Wk, const float* __restrict__ Wv,
    const float* __restrict__ Wo, const float* __restrict__ bq,
    const float* __restrict__ bk, const float* __restrict__ bv,
    bf16_t* __restrict__ xb, bf16_t* __restrict__ Wcat,
    bf16_t* __restrict__ Wob, float* __restrict__ bcat,
    float2* __restrict__ rt)
{
  const int bid = blockIdx.x, tid = threadIdx.x;
  if (bid >= 4099) {
    const int idx = (bid - 4099) * 256 + tid;   // SEQ*32 = 65536 entries
    const int s = idx >> 5, i = idx & 31;
    float inv = powf(10000.0f, -(float)(2 * i) / 64.0f);
    float ang = (float)s * inv;
    rt[idx] = make_float2(cosf(ang), sinf(ang));
    return;
  }
  if (bid >= 4096) {
    const int k = bid - 4096;
    const float* src = (k == 0) ? bq : (k == 1) ? bk : bv;
    *(float4*)&bcat[k * DM + tid * 4] = *(const float4*)&src[tid * 4];
    return;
  }
  const float* src; bf16_t* dst; int i;
  if (bid < 2048)      { src = x;  dst = xb;                i = bid * 2048 + tid * 8; }
  else if (bid < 2560) { src = Wq; dst = Wcat;              i = (bid - 2048) * 2048 + tid * 8; }
  else if (bid < 3072) { src = Wk; dst = Wcat + DM * DM;    i = (bid - 2560) * 2048 + tid * 8; }
  else if (bid < 3584) { src = Wv; dst = Wcat + 2 * DM * DM;i = (bid - 3072) * 2048 + tid * 8; }
  else                 { src = Wo; dst = Wob;               i = (bid - 3584) * 2048 + tid * 8; }
  float4 a = *(const float4*)(src + i);
  float4 b = *(const float4*)(src + i + 4);
  bf16x8 o;
  o[0] = (bf16_t)a.x; o[1] = (bf16_t)a.y; o[2] = (bf16_t)a.z; o[3] = (bf16_t)a.w;
  o[4] = (bf16_t)b.x; o[5] = (bf16_t)b.y; o[6] = (bf16_t)b.z; o[7] = (bf16_t)b.w;
  *(bf16x8*)(dst + i) = o;
}

// ---------------- Q/K projection GEMM (C^T) + bias + RoPE, LDS double-buffered ---
__global__ __launch_bounds__(256) void k_gemm_qk(
    const bf16_t* __restrict__ A, const bf16_t* __restrict__ B,
    const float* __restrict__ bias, const float2* __restrict__ rt,
    bf16_t* __restrict__ Qo, bf16_t* __restrict__ Ko)
{
  const int K = DM;
  __shared__ __align__(16) bf16_t As[2][128 * 32];
  __shared__ __align__(16) bf16_t Bs[2][128 * 32];
  const int tid  = threadIdx.x;
  const int lane = tid & 63;
  const int wave = tid >> 6;
  const int wr = wave >> 1, wc = wave & 1;
  const int m0 = blockIdx.y * 128, n0 = blockIdx.x * 128;
  const int c16 = lane & 15, g = lane >> 4;

  f32x4 acc[4][4];
  #pragma unroll
  for (int i = 0; i < 4; ++i)
    #pragma unroll
    for (int j = 0; j < 4; ++j)
      #pragma unroll
      for (int e = 0; e < 4; ++e) acc[i][j][e] = 0.0f;

  const int srow = wave * 32;
  const int lrow = lane >> 2;
  const int lk   = (lane & 3) * 8;
  const bf16_t* ga0 = A + (size_t)(m0 + srow +      lrow) * K + lk;
  const bf16_t* ga1 = A + (size_t)(m0 + srow + 16 + lrow) * K + lk;
  const bf16_t* gb0 = B + (size_t)(n0 + srow +      lrow) * K + lk;
  const bf16_t* gb1 = B + (size_t)(n0 + srow + 16 + lrow) * K + lk;
  bf16_t* la0A = &As[0][(srow) * 32];      bf16_t* la0B = &As[1][(srow) * 32];
  bf16_t* la1A = &As[0][(srow + 16) * 32]; bf16_t* la1B = &As[1][(srow + 16) * 32];
  bf16_t* lb0A = &Bs[0][(srow) * 32];      bf16_t* lb0B = &Bs[1][(srow) * 32];
  bf16_t* lb1A = &Bs[0][(srow + 16) * 32]; bf16_t* lb1B = &Bs[1][(srow + 16) * 32];

  const int po = (wr * 64 + c16) * 32 + g * 8;
  const int qo = (wc * 64 + c16) * 32 + g * 8;
  const bf16_t* paA = &As[0][po]; const bf16_t* paB = &As[1][po];
  const bf16_t* pbA = &Bs[0][qo]; const bf16_t* pbB = &Bs[1][qo];

  GLOAD_LDS16(ga0, la0A); GLOAD_LDS16(ga1, la1A);
  GLOAD_LDS16(gb0, lb0A); GLOAD_LDS16(gb1, lb1A);
  __syncthreads();

  for (int it = 0; it < K / 32; ++it) {
    const bool odd = it & 1;
    const int kt = it * 32;
    if (kt + 32 < K) {
      GLOAD_LDS16(ga0 + kt + 32, odd ? la0A : la0B);
      GLOAD_LDS16(ga1 + kt + 32, odd ? la1A : la1B);
      GLOAD_LDS16(gb0 + kt + 32, odd ? lb0A : lb0B);
      GLOAD_LDS16(gb1 + kt + 32, odd ? lb1A : lb1B);
    }
    const bf16_t* pa = odd ? paB : paA;
    const bf16_t* pb = odd ? pbB : pbA;
    bf16x8 af[4], bfr[4];
    #pragma unroll
    for (int t = 0; t < 4; ++t) af[t]  = *(const bf16x8*)(pa + t * 16 * 32);
    #pragma unroll
    for (int t = 0; t < 4; ++t) bfr[t] = *(const bf16x8*)(pb + t * 16 * 32);
    #pragma unroll
    for (int i = 0; i < 4; ++i)
      #pragma unroll
      for (int j = 0; j < 4; ++j)
        acc[i][j] = mfma16(bfr[j], af[i], acc[i][j]);   // SWAPPED -> C^T layout
    __syncthreads();
  }

  const int region = n0 >> 10;                 // 0=Q, 1=K
  bf16_t* dst = region ? Ko : Qo;
  const float qs = region ? 1.0f : (0.125f * 1.44269504088896f);
  #pragma unroll
  for (int j = 0; j < 4; ++j) {
    const int nb = n0 + wc * 64 + j * 16 + (g << 2);   // n of e=0
    const float4 bv = *(const float4*)&bias[nb];
    const int h  = (nb >> 6) & 15;
    const int d0 = nb & 63;
    #pragma unroll
    for (int i = 0; i < 4; ++i) {
      const int m = m0 + wr * 64 + i * 16 + c16;
      const int s = m & 2047;
      const int bh = ((m >> 11) << 4) + h;
      const float4 cs = *(const float4*)&rt[(size_t)s * 32 + (d0 >> 1)];
      const float v0 = acc[i][j][0] + bv.x;
      const float v1 = acc[i][j][1] + bv.y;
      const float v2 = acc[i][j][2] + bv.z;
      const float v3 = acc[i][j][3] + bv.w;
      bf16x4 ov;
      ov[0] = (bf16_t)((v0 * cs.x - v1 * cs.y) * qs);
      ov[1] = (bf16_t)((v0 * cs.y + v1 * cs.x) * qs);
      ov[2] = (bf16_t)((v2 * cs.z - v3 * cs.w) * qs);
      ov[3] = (bf16_t)((v2 * cs.w + v3 * cs.z) * qs);
      *(bf16x4*)&dst[((size_t)bh * SEQ + s) * HD + d0] = ov;
    }
  }
}

// ---------------- V projection GEMM + bias + PERMUTED V^T, LDS double-buffered ---
__global__ __launch_bounds__(256) void k_gemm_v(
    const bf16_t* __restrict__ A, const bf16_t* __restrict__ B,
    const float* __restrict__ bias, bf16_t* __restrict__ Vt)
{
  const int K = DM;
  __shared__ __align__(16) bf16_t As[2][128 * 32];
  __shared__ __align__(16) bf16_t Bs[2][128 * 32];
  const int tid  = threadIdx.x;
  const int lane = tid & 63;
  const int wave = tid >> 6;
  const int wr = wave >> 1, wc = wave & 1;
  const int m0 = blockIdx.y * 128, n0 = blockIdx.x * 128;
  const int c16 = lane & 15, g = lane >> 4;

  f32x4 acc[4][4];
  #pragma unroll
  for (int i = 0; i < 4; ++i)
    #pragma unroll
    for (int j = 0; j < 4; ++j)
      #pragma unroll
      for (int e = 0; e < 4; ++e) acc[i][j][e] = 0.0f;

  const int srow = wave * 32;
  const int lrow = lane >> 2;
  const int lk   = (lane & 3) * 8;
  const bf16_t* ga0 = A + (size_t)(m0 + srow +      lrow) * K + lk;
  const bf16_t* ga1 = A + (size_t)(m0 + srow + 16 + lrow) * K + lk;
  const bf16_t* gb0 = B + (size_t)(n0 + srow +      lrow) * K + lk;
  const bf16_t* gb1 = B + (size_t)(n0 + srow + 16 + lrow) * K + lk;
  bf16_t* la0A = &As[0][(srow) * 32];      bf16_t* la0B = &As[1][(srow) * 32];
  bf16_t* la1A = &As[0][(srow + 16) * 32]; bf16_t* la1B = &As[1][(srow + 16) * 32];
  bf16_t* lb0A = &Bs[0][(srow) * 32];      bf16_t* lb0B = &Bs[1][(srow) * 32];
  bf16_t* lb1A = &Bs[0][(srow + 16) * 32]; bf16_t* lb1B = &Bs[1][(srow + 16) * 32];

  const int po = (wr * 64 + c16) * 32 + g * 8;
  const int qo = (wc * 64 + c16) * 32 + g * 8;
  const bf16_t* paA = &As[0][po]; const bf16_t* paB = &As[1][po];
  const bf16_t* pbA = &Bs[0][qo]; const bf16_t* pbB = &Bs[1][qo];

  GLOAD_LDS16(ga0, la0A); GLOAD_LDS16(ga1, la1A);
  GLOAD_LDS16(gb0, lb0A); GLOAD_LDS16(gb1, lb1A);
  __syncthreads();

  for (int it = 0; it < K / 32; ++it) {
    const bool odd = it & 1;
    const int kt = it * 32;
    if (kt + 32 < K) {
      GLOAD_LDS16(ga0 + kt + 32, odd ? la0A : la0B);
      GLOAD_LDS16(ga1 + kt + 32, odd ? la1A : la1B);
      GLOAD_LDS16(gb0 + kt + 32, odd ? lb0A : lb0B);
      GLOAD_LDS16(gb1 + kt + 32, odd ? lb1A : lb1B);
    }
    const bf16_t* pa = odd ? paB : paA;
    const bf16_t* pb = odd ? pbB : pbA;
    bf16x8 af[4], bfr[4];
    #pragma unroll
    for (int t = 0; t < 4; ++t) af[t]  = *(const bf16x8*)(pa + t * 16 * 32);
    #pragma unroll
    for (int t = 0; t < 4; ++t) bfr[t] = *(const bf16x8*)(pb + t * 16 * 32);
    #pragma unroll
    for (int i = 0; i < 4; ++i)
      #pragma unroll
      for (int j = 0; j < 4; ++j)
        acc[i][j] = mfma16(af[i], bfr[j], acc[i][j]);
    __syncthreads();
  }

  const int rbase = m0 + wr * 64 + (g << 2);
  const int cbase = n0 + wc * 64 + c16;
  #pragma unroll
  for (int j = 0; j < 4; ++j) {
    const int c = cbase + j * 16;
    const float bv = bias[c];
    const int h = (c >> 6) & 15;
    const int d = c & 63;
    #pragma unroll
    for (int i = 0; i < 4; ++i) {
      bf16x4 ov;
      #pragma unroll
      for (int e = 0; e < 4; ++e) ov[e] = (bf16_t)(acc[i][j][e] + bv);
      const int r0 = rbase + i * 16;
      const int bh = ((r0 >> 11) << 4) + h;
      const int s0 = r0 & 2047;
      const int u  = (s0 >> 4) & 3;
      const int p0 = (s0 & ~63) + ((u >> 1) << 5) + (g << 3) + ((u & 1) << 2);
      *(bf16x4*)&Vt[((size_t)bh * HD + d) * SEQ + p0] = ov;
    }
  }
}

// ---------------- output projection GEMM: 8 waves, LDS double-buffered ----------
__global__ __launch_bounds__(512) void k_gemm_out(
    const bf16_t* __restrict__ A, const bf16_t* __restrict__ B,
    const float* __restrict__ bias, float* __restrict__ C)
{
  const int K = DM, N = DM;
  __shared__ __align__(16) bf16_t As[2][128 * 32];
  __shared__ __align__(16) bf16_t Bs[2][128 * 32];
  const int tid  = threadIdx.x;
  const int lane = tid & 63;
  const int w    = tid >> 6;
  const int wr = w >> 2, wc = w & 3;
  const int m0 = blockIdx.y * 128, n0 = blockIdx.x * 128;
  const int c16 = lane & 15, g = lane >> 4;

  f32x4 acc[4][2];
  #pragma unroll
  for (int i = 0; i < 4; ++i)
    #pragma unroll
    for (int j = 0; j < 2; ++j)
      #pragma unroll
      for (int e = 0; e < 4; ++e) acc[i][j][e] = 0.0f;

  const int lrow = lane >> 2;
  const int lk   = (lane & 3) * 8;
  const bf16_t* ga = A + (size_t)(m0 + w * 16 + lrow) * K + lk;
  const bf16_t* gb = B + (size_t)(n0 + w * 16 + lrow) * K + lk;
  bf16_t* laA = &As[0][(w * 16) * 32]; bf16_t* laB = &As[1][(w * 16) * 32];
  bf16_t* lbA = &Bs[0][(w * 16) * 32]; bf16_t* lbB = &Bs[1][(w * 16) * 32];

  const int po = (wr * 64 + c16) * 32 + g * 8;
  const int qo = (wc * 32 + c16) * 32 + g * 8;
  const bf16_t* paA = &As[0][po]; const bf16_t* paB = &As[1][po];
  const bf16_t* pbA = &Bs[0][qo]; const bf16_t* pbB = &Bs[1][qo];

  GLOAD_LDS16(ga, laA); GLOAD_LDS16(gb, lbA);
  __syncthreads();

  for (int it = 0; it < K / 32; ++it) {
    const bool odd = it & 1;
    const int kt = it * 32;
    if (kt + 32 < K) {
      GLOAD_LDS16(ga + kt + 32, odd ? laA : laB);
      GLOAD_LDS16(gb + kt + 32, odd ? lbA : lbB);
    }
    const bf16_t* pa = odd ? paB : paA;
    const bf16_t* pb = odd ? pbB : pbA;
    bf16x8 af[4], bfr[2];
    #pragma unroll
    for (int t = 0; t < 4; ++t) af[t]  = *(const bf16x8*)(pa + t * 16 * 32);
    #pragma unroll
    for (int t = 0; t < 2; ++t) bfr[t] = *(const bf16x8*)(pb + t * 16 * 32);
    #pragma unroll
    for (int i = 0; i < 4; ++i)
      #pragma unroll
      for (int j = 0; j < 2; ++j)
        acc[i][j] = mfma16(af[i], bfr[j], acc[i][j]);
    __syncthreads();
  }

  const int rbase = m0 + wr * 64 + (g << 2);
  const int cbase = n0 + wc * 32 + c16;
  #pragma unroll
  for (int j = 0; j < 2; ++j) {
    const int c = cbase + j * 16;
    const float bv = bias[c];
    #pragma unroll
    for (int i = 0; i < 4; ++i) {
      #pragma unroll
      for (int e = 0; e < 4; ++e) {
        const int r = rbase + i * 16 + e;
        C[(size_t)r * N + c] = acc[i][j][e] + bv;
      }
    }
  }
}

// ---------------- flash attention: fused diagonal-pair, 2 tiles per barrier ------
// r17/r19 structure with the barrier count HALVED: 4-slot LDS (2 group-parities x
// 2 tiles), each iteration stages the next 2-tile group and computes 2 tiles
// (A+B sides each) before one __syncthreads. The per-tile compute body is the
// measured-good r19 code, invoked via lambda. LDS 64KB -> still 2 blocks/CU.
__global__ __launch_bounds__(256, 2) void k_attn(
    const bf16_t* __restrict__ Q, const bf16_t* __restrict__ K,
    const bf16_t* __restrict__ Vt, bf16_t* __restrict__ O)
{
  __shared__ __align__(16) bf16_t kls[4 * 4096];   // 4 tile slots x 8KB
  __shared__ __align__(16) bf16_t vls[4 * 4096];
  const int tid = threadIdx.x, lane = tid & 63, w = tid >> 6;
  const int pr = blockIdx.x >> 5;          // 0..15
  const int bh = blockIdx.x & 31;
  const int b  = bh >> 4, h = bh & 15;
  const int c16 = lane & 15;
  const int g   = lane >> 4;

  const bf16_t* Qb = Q  + (size_t)bh * SEQ * HD;
  const bf16_t* Kb = K  + (size_t)bh * SEQ * HD;
  const bf16_t* Vb = Vt + (size_t)bh * HD * SEQ;

  const int qtA = pr, qtB = 31 - pr;
  const int qA  = qtA * 64 + w * 16 + c16;
  const int qB  = qtB * 64 + w * 16 + c16;
  const int Tmax = qtB + 1;                // 32 - pr staged tiles

  bf16x8 qfA0 = *(const bf16x8*)&Qb[(size_t)qA * HD + g * 8];
  bf16x8 qfA1 = *(const bf16x8*)&Qb[(size_t)qA * HD + 32 + g * 8];
  bf16x8 qfB0 = *(const bf16x8*)&Qb[(size_t)qB * HD + g * 8];
  bf16x8 qfB1 = *(const bf16x8*)&Qb[(size_t)qB * HD + 32 + g * 8];

  f32x4 oaccA[4], oaccB[4];
  #pragma unroll
  for (int dblk = 0; dblk < 4; ++dblk)
    #pragma unroll
    for (int e = 0; e < 4; ++e) { oaccA[dblk][e] = 0.0f; oaccB[dblk][e] = 0.0f; }
  float mA = -1e30f, lA = 0.0f, mB = -1e30f, lB = 0.0f;

  // ---- staging addresses (hoisted) ----
  const int soff0 = w * 1024 + lane * 16;
  const int soff1 = soff0 + 4096;
  const int srow0 = soff0 >> 7, srow1 = soff1 >> 7;
  const int scb0  = (soff0 & 127) ^ ((srow0 & 7) << 4);
  const int scb1  = (soff1 & 127) ^ ((srow1 & 7) << 4);
  const bf16_t* gk0 = &Kb[(size_t)srow0 * HD + (scb0 >> 1)];
  const bf16_t* gk1 = &Kb[(size_t)srow1 * HD + (scb1 >> 1)];
  const bf16_t* gv0 = &Vb[(size_t)srow0 * SEQ + (scb0 >> 1)];
  const bf16_t* gv1 = &Vb[(size_t)srow1 * SEQ + (scb1 >> 1)];
  const int wd0 = (w * 1024) >> 1;                 // wave dest elem offset, chunk 0
  const int wd1 = wd0 + 2048;                      // chunk 1

  const int sw = (c16 & 7) << 4;
  const int e0 = ((16 * g) ^ sw) >> 1;
  const int dhi = (((64 + 16 * g) ^ sw) >> 1) - e0;
  const int fro = c16 * 64 + e0;                   // fragment read elem offset

  // stage tile tt into slot ((tt>>1)&1)*2 + (tt&1)
  auto STAGE = [&](int tt) {
    const int slot = (((tt >> 1) & 1) << 1) | (tt & 1);
    const size_t gko = (size_t)tt * 4096;          // 64 rows * 64 d
    const size_t gvo = (size_t)tt * 64;            // 64 kv columns
    GLOAD_LDS16(gk0 + gko, kls + slot * 4096 + wd0);
    GLOAD_LDS16(gk1 + gko, kls + slot * 4096 + wd1);
    GLOAD_LDS16(gv0 + gvo, vls + slot * 4096 + wd0);
    GLOAD_LDS16(gv1 + gvo, vls + slot * 4096 + wd1);
  };

  // compute tile tt (A and B sides) from its slot
  auto COMPUTE = [&](int tt) {
    const int slot = (((tt >> 1) & 1) << 1) | (tt & 1);
    const bf16_t* kp = kls + slot * 4096 + fro;
    const bf16_t* vp = vls + slot * 4096 + fro;

    bf16x8 kf0[4], kf1[4], vlo[4], vhi[4];
    #pragma unroll
    for (int u = 0; u < 4; ++u) {
      kf0[u] = *(const bf16x8*)(kp + u * 1024);
      kf1[u] = *(const bf16x8*)(kp + u * 1024 + dhi);
    }
    #pragma unroll
    for (int dblk = 0; dblk < 4; ++dblk) {
      vlo[dblk] = *(const bf16x8*)(vp + dblk * 1024);
      vhi[dblk] = *(const bf16x8*)(vp + dblk * 1024 + dhi);
    }

    // ---- B side (always active) ----
    {
      f32x4 st[4];
      __builtin_amdgcn_s_setprio(1);
      #pragma unroll
      for (int u = 0; u < 4; ++u) {
        f32x4 z; z[0] = z[1] = z[2] = z[3] = 0.0f;
        z = mfma16(kf0[u], qfB0, z);
        z = mfma16(kf1[u], qfB1, z);
        st[u] = z;
      }
      __builtin_amdgcn_s_setprio(0);

      float pv[16];
      if (tt == qtB) {
        const int kv0 = tt * 64;
        #pragma unroll
        for (int u = 0; u < 4; ++u)
          #pragma unroll
          for (int r = 0; r < 4; ++r) {
            const int kv = kv0 + 16 * u + 4 * g + r;
            pv[u * 4 + r] = (kv <= qB) ? st[u][r] : -1e30f;
          }
      } else {
        #pragma unroll
        for (int u = 0; u < 4; ++u)
          #pragma unroll
          for (int r = 0; r < 4; ++r)
            pv[u * 4 + r] = st[u][r];
      }

      float ma = fmaxf(fmaxf(pv[0], pv[1]), fmaxf(pv[2], pv[3]));
      float mb = fmaxf(fmaxf(pv[4], pv[5]), fmaxf(pv[6], pv[7]));
      float mc = fmaxf(fmaxf(pv[8], pv[9]), fmaxf(pv[10], pv[11]));
      float md = fmaxf(fmaxf(pv[12], pv[13]), fmaxf(pv[14], pv[15]));
      const float lmx = fmaxf(fmaxf(ma, mb), fmaxf(mc, md));

      if (__any(lmx - mB > 12.0f)) {
        float mx = fmaxf(lmx, __shfl_xor(lmx, 16));
        mx = fmaxf(mx, __shfl_xor(mx, 32));
        const float mn = fmaxf(mB, mx);
        const float alpha = exp2f(mB - mn);
        lB *= alpha;
        #pragma unroll
        for (int dblk = 0; dblk < 4; ++dblk)
          #pragma unroll
          for (int e = 0; e < 4; ++e) oaccB[dblk][e] *= alpha;
        mB = mn;
      }

      #pragma unroll
      for (int i = 0; i < 16; ++i) pv[i] = exp2f(pv[i] - mB);
      float s0 = (pv[0] + pv[1]) + (pv[2] + pv[3]);
      float s1 = (pv[4] + pv[5]) + (pv[6] + pv[7]);
      float s2 = (pv[8] + pv[9]) + (pv[10] + pv[11]);
      float s3 = (pv[12] + pv[13]) + (pv[14] + pv[15]);
      lB += (s0 + s1) + (s2 + s3);

      bf16x8 pf0, pf1;
      #pragma unroll
      for (int j = 0; j < 8; ++j) {
        pf0[j] = (bf16_t)pv[j];
        pf1[j] = (bf16_t)pv[8 + j];
      }

      __builtin_amdgcn_s_setprio(1);
      #pragma unroll
      for (int dblk = 0; dblk < 4; ++dblk) {
        oaccB[dblk] = mfma16(vlo[dblk], pf0, oaccB[dblk]);
        oaccB[dblk] = mfma16(vhi[dblk], pf1, oaccB[dblk]);
      }
      __builtin_amdgcn_s_setprio(0);
    }

    // ---- A side (active while tt <= qtA; block-uniform) ----
    if (tt <= qtA) {
      f32x4 st[4];
      __builtin_amdgcn_s_setprio(1);
      #pragma unroll
      for (int u = 0; u < 4; ++u) {
        f32x4 z; z[0] = z[1] = z[2] = z[3] = 0.0f;
        z = mfma16(kf0[u], qfA0, z);
        z = mfma16(kf1[u], qfA1, z);
        st[u] = z;
      }
      __builtin_amdgcn_s_setprio(0);

      float pv[16];
      if (tt == qtA) {
        const int kv0 = tt * 64;
        #pragma unroll
        for (int u = 0; u < 4; ++u)
          #pragma unroll
          for (int r = 0; r < 4; ++r) {
            const int kv = kv0 + 16 * u + 4 * g + r;
            pv[u * 4 + r] = (kv <= qA) ? st[u][r] : -1e30f;
          }
      } else {
        #pragma unroll
        for (int u = 0; u < 4; ++u)
          #pragma unroll
          for (int r = 0; r < 4; ++r)
            pv[u * 4 + r] = st[u][r];
      }

      float ma = fmaxf(fmaxf(pv[0], pv[1]), fmaxf(pv[2], pv[3]));
      float mb = fmaxf(fmaxf(pv[4], pv[5]), fmaxf(pv[6], pv[7]));
      float mc = fmaxf(fmaxf(pv[8], pv[9]), fmaxf(pv[10], pv[11]));
      float md = fmaxf(fmaxf(pv[12], pv[13]), fmaxf(pv[14], pv[15]));
      const float lmx = fmaxf(fmaxf(ma, mb), fmaxf(mc, md));

      if (__any(lmx - mA > 12.0f)) {
        float mx = fmaxf(lmx, __shfl_xor(lmx, 16));
        mx = fmaxf(mx, __shfl_xor(mx, 32));
        const float mn = fmaxf(mA, mx);
        const float alpha = exp2f(mA - mn);
        lA *= alpha;
        #pragma unroll
        for (int dblk = 0; dblk < 4; ++dblk)
          #pragma unroll
          for (int e = 0; e < 4; ++e) oaccA[dblk][e] *= alpha;
        mA = mn;
      }

      #pragma unroll
      for (int i = 0; i < 16; ++i) pv[i] = exp2f(pv[i] - mA);
      float s0 = (pv[0] + pv[1]) + (pv[2] + pv[3]);
      float s1 = (pv[4] + pv[5]) + (pv[6] + pv[7]);
      float s2 = (pv[8] + pv[9]) + (pv[10] + pv[11]);
      float s3 = (pv[12] + pv[13]) + (pv[14] + pv[15]);
      lA += (s0 + s1) + (s2 + s3);

      bf16x8 pf0, pf1;
      #pragma unroll
      for (int j = 0; j < 8; ++j) {
        pf0[j] = (bf16_t)pv[j];
        pf1[j] = (bf16_t)pv[8 + j];
      }

      __builtin_amdgcn_s_setprio(1);
      #pragma unroll
      for (int dblk = 0; dblk < 4; ++dblk) {
        oaccA[dblk] = mfma16(vlo[dblk], pf0, oaccA[dblk]);
        oaccA[dblk] = mfma16(vhi[dblk], pf1, oaccA[dblk]);
      }
      __builtin_amdgcn_s_setprio(0);
    }
  };

  // ---- prologue: stage group 0 ----
  STAGE(0);
  if (1 < Tmax) STAGE(1);
  __syncthreads();

  const int ngrp = (Tmax + 1) >> 1;
  for (int gp = 0; gp < ngrp; ++gp) {
    const int t0 = 2 * gp;
    if (t0 + 2 < Tmax) STAGE(t0 + 2);
    if (t0 + 3 < Tmax) STAGE(t0 + 3);
    COMPUTE(t0);
    if (t0 + 1 < Tmax) COMPUTE(t0 + 1);
    __syncthreads();
  }

  // ---- epilogues ----
  lA += __shfl_xor(lA, 16);
  lA += __shfl_xor(lA, 32);
  lB += __shfl_xor(lB, 16);
  lB += __shfl_xor(lB, 32);
  const float invA = 1.0f / lA;
  const float invB = 1.0f / lB;
  bf16_t* orowA = O + ((size_t)(b * SEQ + qA)) * DM + h * HD;
  bf16_t* orowB = O + ((size_t)(b * SEQ + qB)) * DM + h * HD;
  #pragma unroll
  for (int dblk = 0; dblk < 4; ++dblk) {
    bf16x4 ovA, ovB;
    #pragma unroll
    for (int r = 0; r < 4; ++r) {
      ovA[r] = (bf16_t)(oaccA[dblk][r] * invA);
      ovB[r] = (bf16_t)(oaccB[dblk][r] * invB);
    }
    *(bf16x4*)&orowA[dblk * 16 + 4 * g] = ovA;
    *(bf16x4*)&orowB[dblk * 16 + 4 * g] = ovB;
  }
}

// ---------------- launch ----------------
extern "C" void kernel_launch(void* const* d_in, const int* in_sizes, int n_in,
                              void* d_out, int out_size, void* d_ws, size_t ws_size,
                              hipStream_t stream)
{
  const float* x  = (const float*)d_in[0];
  const float* Wq = (const float*)d_in[1];
  const float* bq = (const float*)d_in[2];
  const float* Wk = (const float*)d_in[3];
  const float* bk = (const float*)d_in[4];
  const float* Wv = (const float*)d_in[5];
  const float* bv = (const float*)d_in[6];
  const float* Wo = (const float*)d_in[7];
  const float* bo = (const float*)d_in[8];
  float* out = (float*)d_out;

  char* ws = (char*)d_ws;
  size_t off = 0;
  auto alloc = [&](size_t bytes) { char* p = ws + off; off += (bytes + 255) & ~255ULL; return p; };
  bf16_t* xb   = (bf16_t*)alloc((size_t)BS * DM * 2);
  bf16_t* Wcat = (bf16_t*)alloc((size_t)NQKV * DM * 2);
  bf16_t* Wob  = (bf16_t*)alloc((size_t)DM * DM * 2);
  float*  bcat = (float*)alloc((size_t)NQKV * 4);
  float2* rt   = (float2*)alloc((size_t)SEQ * 32 * 8);
  bf16_t* Qh   = (bf16_t*)alloc((size_t)BS * DM * 2);
  bf16_t* Kh   = (bf16_t*)alloc((size_t)BS * DM * 2);
  bf16_t* Vth  = (bf16_t*)alloc((size_t)BS * DM * 2);
  bf16_t* Oh   = (bf16_t*)alloc((size_t)BS * DM * 2);
  (void)ws_size; (void)in_sizes; (void)n_in; (void)out_size;

  k_cast_all<<<4099 + 256, 256, 0, stream>>>(x, Wq, Wk, Wv, Wo, bq, bk, bv,
                                             xb, Wcat, Wob, bcat, rt);

  dim3 gqk(16, 32);
  k_gemm_qk<<<gqk, 256, 0, stream>>>(xb, Wcat, bcat, rt, Qh, Kh);
  dim3 gv(8, 32);
  k_gemm_v<<<gv, 256, 0, stream>>>(xb, Wcat + 2 * DM * DM, bcat + 2 * DM, Vth);
  k_attn<<<512, 256, 0, stream>>>(Qh, Kh, Vth, Oh);
  dim3 g2(DM / 128, BS / 128);
  k_gemm_out<<<g2, 512, 0, stream>>>(Oh, Wob, bo, out);
}

// Round 21
// 118.201 us; speedup vs baseline: 1.0464x; 1.0464x over previous
//
#include <hip/hip_runtime.h>
#include <hip/hip_bf16.h>
#include <stdint.h>

typedef __bf16 bf16_t;
typedef __bf16 bf16x4 __attribute__((ext_vector_type(4)));
typedef __bf16 bf16x8 __attribute__((ext_vector_type(8)));
typedef float  f32x4  __attribute__((ext_vector_type(4)));

#define DM    1024
#define NH    16
#define HD    64
#define SEQ   2048
#define BATCH 2
#define BS    (BATCH*SEQ)   // 4096
#define NQKV  (3*DM)        // 3072

#define GLOAD_LDS16(g, l) \
  __builtin_amdgcn_global_load_lds((const __attribute__((address_space(1))) void*)(g), \
                                   (__attribute__((address_space(3))) void*)(l), 16, 0, 0)

__device__ __forceinline__ f32x4 mfma16(bf16x8 a, bf16x8 b, f32x4 c) {
  return __builtin_amdgcn_mfma_f32_16x16x32_bf16(a, b, c, 0, 0, 0);
}

// ---------------- merged cast/copy + rope-table kernel ----------------
__global__ __launch_bounds__(256) void k_cast_all(
    const float* __restrict__ x,  const float* __restrict__ Wq,
    const float* __restrict__ Wk, const float* __restrict__ Wv,
    const float* __restrict__ Wo, const float* __restrict__ bq,
    const float* __restrict__ bk, const float* __restrict__ bv,
    bf16_t* __restrict__ xb, bf16_t* __restrict__ Wcat,
    bf16_t* __restrict__ Wob, float* __restrict__ bcat,
    float2* __restrict__ rt)
{
  const int bid = blockIdx.x, tid = threadIdx.x;
  if (bid >= 4099) {
    const int idx = (bid - 4099) * 256 + tid;   // SEQ*32 = 65536 entries
    const int s = idx >> 5, i = idx & 31;
    float inv = powf(10000.0f, -(float)(2 * i) / 64.0f);
    float ang = (float)s * inv;
    rt[idx] = make_float2(cosf(ang), sinf(ang));
    return;
  }
  if (bid >= 4096) {
    const int k = bid - 4096;
    const float* src = (k == 0) ? bq : (k == 1) ? bk : bv;
    *(float4*)&bcat[k * DM + tid * 4] = *(const float4*)&src[tid * 4];
    return;
  }
  const float* src; bf16_t* dst; int i;
  if (bid < 2048)      { src = x;  dst = xb;                i = bid * 2048 + tid * 8; }
  else if (bid < 2560) { src = Wq; dst = Wcat;              i = (bid - 2048) * 2048 + tid * 8; }
  else if (bid < 3072) { src = Wk; dst = Wcat + DM * DM;    i = (bid - 2560) * 2048 + tid * 8; }
  else if (bid < 3584) { src = Wv; dst = Wcat + 2 * DM * DM;i = (bid - 3072) * 2048 + tid * 8; }
  else                 { src = Wo; dst = Wob;               i = (bid - 3584) * 2048 + tid * 8; }
  float4 a = *(const float4*)(src + i);
  float4 b = *(const float4*)(src + i + 4);
  bf16x8 o;
  o[0] = (bf16_t)a.x; o[1] = (bf16_t)a.y; o[2] = (bf16_t)a.z; o[3] = (bf16_t)a.w;
  o[4] = (bf16_t)b.x; o[5] = (bf16_t)b.y; o[6] = (bf16_t)b.z; o[7] = (bf16_t)b.w;
  *(bf16x8*)(dst + i) = o;
}

// ---------------- Q/K projection GEMM (C^T) + bias + RoPE, dbuf + XCD swizzle ----
__global__ __launch_bounds__(256) void k_gemm_qk(
    const bf16_t* __restrict__ A, const bf16_t* __restrict__ B,
    const float* __restrict__ bias, const float2* __restrict__ rt,
    bf16_t* __restrict__ Qo, bf16_t* __restrict__ Ko)
{
  const int K = DM;
  __shared__ __align__(16) bf16_t As[2][128 * 32];
  __shared__ __align__(16) bf16_t Bs[2][128 * 32];
  const int tid  = threadIdx.x;
  const int lane = tid & 63;
  const int wave = tid >> 6;
  const int wr = wave >> 1, wc = wave & 1;
  // T1 XCD swizzle: nwg=512, bijective (512%8==0). Same-XCD blocks contiguous.
  const int orig = blockIdx.y * 16 + blockIdx.x;
  const int wid  = (orig & 7) * 64 + (orig >> 3);
  const int m0 = (wid >> 4) * 128, n0 = (wid & 15) * 128;
  const int c16 = lane & 15, g = lane >> 4;

  f32x4 acc[4][4];
  #pragma unroll
  for (int i = 0; i < 4; ++i)
    #pragma unroll
    for (int j = 0; j < 4; ++j)
      #pragma unroll
      for (int e = 0; e < 4; ++e) acc[i][j][e] = 0.0f;

  const int srow = wave * 32;
  const int lrow = lane >> 2;
  const int lk   = (lane & 3) * 8;
  const bf16_t* ga0 = A + (size_t)(m0 + srow +      lrow) * K + lk;
  const bf16_t* ga1 = A + (size_t)(m0 + srow + 16 + lrow) * K + lk;
  const bf16_t* gb0 = B + (size_t)(n0 + srow +      lrow) * K + lk;
  const bf16_t* gb1 = B + (size_t)(n0 + srow + 16 + lrow) * K + lk;
  bf16_t* la0A = &As[0][(srow) * 32];      bf16_t* la0B = &As[1][(srow) * 32];
  bf16_t* la1A = &As[0][(srow + 16) * 32]; bf16_t* la1B = &As[1][(srow + 16) * 32];
  bf16_t* lb0A = &Bs[0][(srow) * 32];      bf16_t* lb0B = &Bs[1][(srow) * 32];
  bf16_t* lb1A = &Bs[0][(srow + 16) * 32]; bf16_t* lb1B = &Bs[1][(srow + 16) * 32];

  const int po = (wr * 64 + c16) * 32 + g * 8;
  const int qo = (wc * 64 + c16) * 32 + g * 8;
  const bf16_t* paA = &As[0][po]; const bf16_t* paB = &As[1][po];
  const bf16_t* pbA = &Bs[0][qo]; const bf16_t* pbB = &Bs[1][qo];

  GLOAD_LDS16(ga0, la0A); GLOAD_LDS16(ga1, la1A);
  GLOAD_LDS16(gb0, lb0A); GLOAD_LDS16(gb1, lb1A);
  __syncthreads();

  for (int it = 0; it < K / 32; ++it) {
    const bool odd = it & 1;
    const int kt = it * 32;
    if (kt + 32 < K) {
      GLOAD_LDS16(ga0 + kt + 32, odd ? la0A : la0B);
      GLOAD_LDS16(ga1 + kt + 32, odd ? la1A : la1B);
      GLOAD_LDS16(gb0 + kt + 32, odd ? lb0A : lb0B);
      GLOAD_LDS16(gb1 + kt + 32, odd ? lb1A : lb1B);
    }
    const bf16_t* pa = odd ? paB : paA;
    const bf16_t* pb = odd ? pbB : pbA;
    bf16x8 af[4], bfr[4];
    #pragma unroll
    for (int t = 0; t < 4; ++t) af[t]  = *(const bf16x8*)(pa + t * 16 * 32);
    #pragma unroll
    for (int t = 0; t < 4; ++t) bfr[t] = *(const bf16x8*)(pb + t * 16 * 32);
    #pragma unroll
    for (int i = 0; i < 4; ++i)
      #pragma unroll
      for (int j = 0; j < 4; ++j)
        acc[i][j] = mfma16(bfr[j], af[i], acc[i][j]);   // SWAPPED -> C^T layout
    __syncthreads();
  }

  const int region = n0 >> 10;                 // 0=Q, 1=K
  bf16_t* dst = region ? Ko : Qo;
  const float qs = region ? 1.0f : (0.125f * 1.44269504088896f);
  #pragma unroll
  for (int j = 0; j < 4; ++j) {
    const int nb = n0 + wc * 64 + j * 16 + (g << 2);   // n of e=0
    const float4 bv = *(const float4*)&bias[nb];
    const int h  = (nb >> 6) & 15;
    const int d0 = nb & 63;
    #pragma unroll
    for (int i = 0; i < 4; ++i) {
      const int m = m0 + wr * 64 + i * 16 + c16;
      const int s = m & 2047;
      const int bh = ((m >> 11) << 4) + h;
      const float4 cs = *(const float4*)&rt[(size_t)s * 32 + (d0 >> 1)];
      const float v0 = acc[i][j][0] + bv.x;
      const float v1 = acc[i][j][1] + bv.y;
      const float v2 = acc[i][j][2] + bv.z;
      const float v3 = acc[i][j][3] + bv.w;
      bf16x4 ov;
      ov[0] = (bf16_t)((v0 * cs.x - v1 * cs.y) * qs);
      ov[1] = (bf16_t)((v0 * cs.y + v1 * cs.x) * qs);
      ov[2] = (bf16_t)((v2 * cs.z - v3 * cs.w) * qs);
      ov[3] = (bf16_t)((v2 * cs.w + v3 * cs.z) * qs);
      *(bf16x4*)&dst[((size_t)bh * SEQ + s) * HD + d0] = ov;
    }
  }
}

// ---------------- V projection GEMM + bias + PERMUTED V^T, dbuf + XCD swizzle ----
__global__ __launch_bounds__(256) void k_gemm_v(
    const bf16_t* __restrict__ A, const bf16_t* __restrict__ B,
    const float* __restrict__ bias, bf16_t* __restrict__ Vt)
{
  const int K = DM;
  __shared__ __align__(16) bf16_t As[2][128 * 32];
  __shared__ __align__(16) bf16_t Bs[2][128 * 32];
  const int tid  = threadIdx.x;
  const int lane = tid & 63;
  const int wave = tid >> 6;
  const int wr = wave >> 1, wc = wave & 1;
  // T1 XCD swizzle: nwg=256
  const int orig = blockIdx.y * 8 + blockIdx.x;
  const int wid  = (orig & 7) * 32 + (orig >> 3);
  const int m0 = (wid >> 3) * 128, n0 = (wid & 7) * 128;
  const int c16 = lane & 15, g = lane >> 4;

  f32x4 acc[4][4];
  #pragma unroll
  for (int i = 0; i < 4; ++i)
    #pragma unroll
    for (int j = 0; j < 4; ++j)
      #pragma unroll
      for (int e = 0; e < 4; ++e) acc[i][j][e] = 0.0f;

  const int srow = wave * 32;
  const int lrow = lane >> 2;
  const int lk   = (lane & 3) * 8;
  const bf16_t* ga0 = A + (size_t)(m0 + srow +      lrow) * K + lk;
  const bf16_t* ga1 = A + (size_t)(m0 + srow + 16 + lrow) * K + lk;
  const bf16_t* gb0 = B + (size_t)(n0 + srow +      lrow) * K + lk;
  const bf16_t* gb1 = B + (size_t)(n0 + srow + 16 + lrow) * K + lk;
  bf16_t* la0A = &As[0][(srow) * 32];      bf16_t* la0B = &As[1][(srow) * 32];
  bf16_t* la1A = &As[0][(srow + 16) * 32]; bf16_t* la1B = &As[1][(srow + 16) * 32];
  bf16_t* lb0A = &Bs[0][(srow) * 32];      bf16_t* lb0B = &Bs[1][(srow) * 32];
  bf16_t* lb1A = &Bs[0][(srow + 16) * 32]; bf16_t* lb1B = &Bs[1][(srow + 16) * 32];

  const int po = (wr * 64 + c16) * 32 + g * 8;
  const int qo = (wc * 64 + c16) * 32 + g * 8;
  const bf16_t* paA = &As[0][po]; const bf16_t* paB = &As[1][po];
  const bf16_t* pbA = &Bs[0][qo]; const bf16_t* pbB = &Bs[1][qo];

  GLOAD_LDS16(ga0, la0A); GLOAD_LDS16(ga1, la1A);
  GLOAD_LDS16(gb0, lb0A); GLOAD_LDS16(gb1, lb1A);
  __syncthreads();

  for (int it = 0; it < K / 32; ++it) {
    const bool odd = it & 1;
    const int kt = it * 32;
    if (kt + 32 < K) {
      GLOAD_LDS16(ga0 + kt + 32, odd ? la0A : la0B);
      GLOAD_LDS16(ga1 + kt + 32, odd ? la1A : la1B);
      GLOAD_LDS16(gb0 + kt + 32, odd ? lb0A : lb0B);
      GLOAD_LDS16(gb1 + kt + 32, odd ? lb1A : lb1B);
    }
    const bf16_t* pa = odd ? paB : paA;
    const bf16_t* pb = odd ? pbB : pbA;
    bf16x8 af[4], bfr[4];
    #pragma unroll
    for (int t = 0; t < 4; ++t) af[t]  = *(const bf16x8*)(pa + t * 16 * 32);
    #pragma unroll
    for (int t = 0; t < 4; ++t) bfr[t] = *(const bf16x8*)(pb + t * 16 * 32);
    #pragma unroll
    for (int i = 0; i < 4; ++i)
      #pragma unroll
      for (int j = 0; j < 4; ++j)
        acc[i][j] = mfma16(af[i], bfr[j], acc[i][j]);
    __syncthreads();
  }

  const int rbase = m0 + wr * 64 + (g << 2);
  const int cbase = n0 + wc * 64 + c16;
  #pragma unroll
  for (int j = 0; j < 4; ++j) {
    const int c = cbase + j * 16;
    const float bv = bias[c];
    const int h = (c >> 6) & 15;
    const int d = c & 63;
    #pragma unroll
    for (int i = 0; i < 4; ++i) {
      bf16x4 ov;
      #pragma unroll
      for (int e = 0; e < 4; ++e) ov[e] = (bf16_t)(acc[i][j][e] + bv);
      const int r0 = rbase + i * 16;
      const int bh = ((r0 >> 11) << 4) + h;
      const int s0 = r0 & 2047;
      const int u  = (s0 >> 4) & 3;
      const int p0 = (s0 & ~63) + ((u >> 1) << 5) + (g << 3) + ((u & 1) << 2);
      *(bf16x4*)&Vt[((size_t)bh * HD + d) * SEQ + p0] = ov;
    }
  }
}

// ---------------- output projection GEMM: 8 waves, dbuf + XCD swizzle -----------
__global__ __launch_bounds__(512) void k_gemm_out(
    const bf16_t* __restrict__ A, const bf16_t* __restrict__ B,
    const float* __restrict__ bias, float* __restrict__ C)
{
  const int K = DM, N = DM;
  __shared__ __align__(16) bf16_t As[2][128 * 32];
  __shared__ __align__(16) bf16_t Bs[2][128 * 32];
  const int tid  = threadIdx.x;
  const int lane = tid & 63;
  const int w    = tid >> 6;
  const int wr = w >> 2, wc = w & 3;
  // T1 XCD swizzle: nwg=256
  const int orig = blockIdx.y * 8 + blockIdx.x;
  const int wid  = (orig & 7) * 32 + (orig >> 3);
  const int m0 = (wid >> 3) * 128, n0 = (wid & 7) * 128;
  const int c16 = lane & 15, g = lane >> 4;

  f32x4 acc[4][2];
  #pragma unroll
  for (int i = 0; i < 4; ++i)
    #pragma unroll
    for (int j = 0; j < 2; ++j)
      #pragma unroll
      for (int e = 0; e < 4; ++e) acc[i][j][e] = 0.0f;

  const int lrow = lane >> 2;
  const int lk   = (lane & 3) * 8;
  const bf16_t* ga = A + (size_t)(m0 + w * 16 + lrow) * K + lk;
  const bf16_t* gb = B + (size_t)(n0 + w * 16 + lrow) * K + lk;
  bf16_t* laA = &As[0][(w * 16) * 32]; bf16_t* laB = &As[1][(w * 16) * 32];
  bf16_t* lbA = &Bs[0][(w * 16) * 32]; bf16_t* lbB = &Bs[1][(w * 16) * 32];

  const int po = (wr * 64 + c16) * 32 + g * 8;
  const int qo = (wc * 32 + c16) * 32 + g * 8;
  const bf16_t* paA = &As[0][po]; const bf16_t* paB = &As[1][po];
  const bf16_t* pbA = &Bs[0][qo]; const bf16_t* pbB = &Bs[1][qo];

  GLOAD_LDS16(ga, laA); GLOAD_LDS16(gb, lbA);
  __syncthreads();

  for (int it = 0; it < K / 32; ++it) {
    const bool odd = it & 1;
    const int kt = it * 32;
    if (kt + 32 < K) {
      GLOAD_LDS16(ga + kt + 32, odd ? laA : laB);
      GLOAD_LDS16(gb + kt + 32, odd ? lbA : lbB);
    }
    const bf16_t* pa = odd ? paB : paA;
    const bf16_t* pb = odd ? pbB : pbA;
    bf16x8 af[4], bfr[2];
    #pragma unroll
    for (int t = 0; t < 4; ++t) af[t]  = *(const bf16x8*)(pa + t * 16 * 32);
    #pragma unroll
    for (int t = 0; t < 2; ++t) bfr[t] = *(const bf16x8*)(pb + t * 16 * 32);
    #pragma unroll
    for (int i = 0; i < 4; ++i)
      #pragma unroll
      for (int j = 0; j < 2; ++j)
        acc[i][j] = mfma16(af[i], bfr[j], acc[i][j]);
    __syncthreads();
  }

  const int rbase = m0 + wr * 64 + (g << 2);
  const int cbase = n0 + wc * 32 + c16;
  #pragma unroll
  for (int j = 0; j < 2; ++j) {
    const int c = cbase + j * 16;
    const float bv = bias[c];
    #pragma unroll
    for (int i = 0; i < 4; ++i) {
      #pragma unroll
      for (int e = 0; e < 4; ++e) {
        const int r = rbase + i * 16 + e;
        C[(size_t)r * N + c] = acc[i][j][e] + bv;
      }
    }
  }
}

// ---------------- flash attention: fused diagonal-pair (r19 best: 42.6 us) -------
__global__ __launch_bounds__(256, 2) void k_attn(
    const bf16_t* __restrict__ Q, const bf16_t* __restrict__ K,
    const bf16_t* __restrict__ Vt, bf16_t* __restrict__ O)
{
  __shared__ __align__(16) bf16_t kbuf[2][64 * 64];
  __shared__ __align__(16) bf16_t vbuf[2][64 * 64];
  const int tid = threadIdx.x, lane = tid & 63, w = tid >> 6;
  const int pr = blockIdx.x >> 5;          // 0..15
  const int bh = blockIdx.x & 31;
  const int b  = bh >> 4, h = bh & 15;
  const int c16 = lane & 15;
  const int g   = lane >> 4;

  const bf16_t* Qb = Q  + (size_t)bh * SEQ * HD;
  const bf16_t* Kb = K  + (size_t)bh * SEQ * HD;
  const bf16_t* Vb = Vt + (size_t)bh * HD * SEQ;

  const int qtA = pr, qtB = 31 - pr;
  const int qA  = qtA * 64 + w * 16 + c16;
  const int qB  = qtB * 64 + w * 16 + c16;
  const int Tmax = qtB + 1;                // 32 - pr staged tiles

  bf16x8 qfA0 = *(const bf16x8*)&Qb[(size_t)qA * HD + g * 8];
  bf16x8 qfA1 = *(const bf16x8*)&Qb[(size_t)qA * HD + 32 + g * 8];
  bf16x8 qfB0 = *(const bf16x8*)&Qb[(size_t)qB * HD + g * 8];
  bf16x8 qfB1 = *(const bf16x8*)&Qb[(size_t)qB * HD + 32 + g * 8];

  f32x4 oaccA[4], oaccB[4];
  #pragma unroll
  for (int dblk = 0; dblk < 4; ++dblk)
    #pragma unroll
    for (int e = 0; e < 4; ++e) { oaccA[dblk][e] = 0.0f; oaccB[dblk][e] = 0.0f; }
  float mA = -1e30f, lA = 0.0f, mB = -1e30f, lB = 0.0f;

  const int soff0 = w * 1024 + lane * 16;
  const int soff1 = soff0 + 4096;
  const int srow0 = soff0 >> 7, srow1 = soff1 >> 7;
  const int scb0  = (soff0 & 127) ^ ((srow0 & 7) << 4);
  const int scb1  = (soff1 & 127) ^ ((srow1 & 7) << 4);
  const bf16_t* gk0 = &Kb[(size_t)srow0 * HD + (scb0 >> 1)];
  const bf16_t* gk1 = &Kb[(size_t)srow1 * HD + (scb1 >> 1)];
  const bf16_t* gv0 = &Vb[(size_t)srow0 * SEQ + (scb0 >> 1)];
  const bf16_t* gv1 = &Vb[(size_t)srow1 * SEQ + (scb1 >> 1)];
  bf16_t* lk0A = &kbuf[0][(w * 1024) >> 1];
  bf16_t* lk1A = &kbuf[0][(w * 1024 + 4096) >> 1];
  bf16_t* lk0B = &kbuf[1][(w * 1024) >> 1];
  bf16_t* lk1B = &kbuf[1][(w * 1024 + 4096) >> 1];
  bf16_t* lv0A = &vbuf[0][(w * 1024) >> 1];
  bf16_t* lv1A = &vbuf[0][(w * 1024 + 4096) >> 1];
  bf16_t* lv0B = &vbuf[1][(w * 1024) >> 1];
  bf16_t* lv1B = &vbuf[1][(w * 1024 + 4096) >> 1];

  const int sw = (c16 & 7) << 4;
  const int e0 = ((16 * g) ^ sw) >> 1;
  const int dhi = (((64 + 16 * g) ^ sw) >> 1) - e0;
  const bf16_t* kp0 = &kbuf[0][c16 * 64 + e0];
  const bf16_t* kp1 = &kbuf[1][c16 * 64 + e0];
  const bf16_t* vp0 = &vbuf[0][c16 * 64 + e0];
  const bf16_t* vp1 = &vbuf[1][c16 * 64 + e0];

  GLOAD_LDS16(gk0, lk0A); GLOAD_LDS16(gk1, lk1A);
  GLOAD_LDS16(gv0, lv0A); GLOAD_LDS16(gv1, lv1A);
  gk0 += 4096; gk1 += 4096; gv0 += 64; gv1 += 64;
  __syncthreads();

  for (int t = 0; t < Tmax; ++t) {
    const bool odd = t & 1;
    if (t + 1 < Tmax) {
      GLOAD_LDS16(gk0, odd ? lk0A : lk0B); GLOAD_LDS16(gk1, odd ? lk1A : lk1B);
      GLOAD_LDS16(gv0, odd ? lv0A : lv0B); GLOAD_LDS16(gv1, odd ? lv1A : lv1B);
      gk0 += 4096; gk1 += 4096; gv0 += 64; gv1 += 64;
    }

    const bf16_t* kp = odd ? kp1 : kp0;
    const bf16_t* vp = odd ? vp1 : vp0;

    // ---- HOISTED fragment loads: 16 ds_read_b128, shared by A and B sides ----
    bf16x8 kf0[4], kf1[4], vlo[4], vhi[4];
    #pragma unroll
    for (int u = 0; u < 4; ++u) {
      kf0[u] = *(const bf16x8*)(kp + u * 1024);
      kf1[u] = *(const bf16x8*)(kp + u * 1024 + dhi);
    }
    #pragma unroll
    for (int dblk = 0; dblk < 4; ++dblk) {
      vlo[dblk] = *(const bf16x8*)(vp + dblk * 1024);
      vhi[dblk] = *(const bf16x8*)(vp + dblk * 1024 + dhi);
    }

    // ================= B side (always active) =================
    {
      f32x4 st[4];
      __builtin_amdgcn_s_setprio(1);
      #pragma unroll
      for (int u = 0; u < 4; ++u) {
        f32x4 z; z[0] = z[1] = z[2] = z[3] = 0.0f;
        z = mfma16(kf0[u], qfB0, z);
        z = mfma16(kf1[u], qfB1, z);
        st[u] = z;
      }
      __builtin_amdgcn_s_setprio(0);

      float pv[16];
      if (t == qtB) {
        const int kv0 = t * 64;
        #pragma unroll
        for (int u = 0; u < 4; ++u)
          #pragma unroll
          for (int r = 0; r < 4; ++r) {
            const int kv = kv0 + 16 * u + 4 * g + r;
            pv[u * 4 + r] = (kv <= qB) ? st[u][r] : -1e30f;
          }
      } else {
        #pragma unroll
        for (int u = 0; u < 4; ++u)
          #pragma unroll
          for (int r = 0; r < 4; ++r)
            pv[u * 4 + r] = st[u][r];
      }

      float ma = fmaxf(fmaxf(pv[0], pv[1]), fmaxf(pv[2], pv[3]));
      float mb = fmaxf(fmaxf(pv[4], pv[5]), fmaxf(pv[6], pv[7]));
      float mc = fmaxf(fmaxf(pv[8], pv[9]), fmaxf(pv[10], pv[11]));
      float md = fmaxf(fmaxf(pv[12], pv[13]), fmaxf(pv[14], pv[15]));
      const float lmx = fmaxf(fmaxf(ma, mb), fmaxf(mc, md));

      if (__any(lmx - mB > 12.0f)) {
        float mx = fmaxf(lmx, __shfl_xor(lmx, 16));
        mx = fmaxf(mx, __shfl_xor(mx, 32));
        const float mn = fmaxf(mB, mx);
        const float alpha = exp2f(mB - mn);
        lB *= alpha;
        #pragma unroll
        for (int dblk = 0; dblk < 4; ++dblk)
          #pragma unroll
          for (int e = 0; e < 4; ++e) oaccB[dblk][e] *= alpha;
        mB = mn;
      }

      #pragma unroll
      for (int i = 0; i < 16; ++i) pv[i] = exp2f(pv[i] - mB);
      float s0 = (pv[0] + pv[1]) + (pv[2] + pv[3]);
      float s1 = (pv[4] + pv[5]) + (pv[6] + pv[7]);
      float s2 = (pv[8] + pv[9]) + (pv[10] + pv[11]);
      float s3 = (pv[12] + pv[13]) + (pv[14] + pv[15]);
      lB += (s0 + s1) + (s2 + s3);

      bf16x8 pf0, pf1;
      #pragma unroll
      for (int j = 0; j < 8; ++j) {
        pf0[j] = (bf16_t)pv[j];
        pf1[j] = (bf16_t)pv[8 + j];
      }

      __builtin_amdgcn_s_setprio(1);
      #pragma unroll
      for (int dblk = 0; dblk < 4; ++dblk) {
        oaccB[dblk] = mfma16(vlo[dblk], pf0, oaccB[dblk]);
        oaccB[dblk] = mfma16(vhi[dblk], pf1, oaccB[dblk]);
      }
      __builtin_amdgcn_s_setprio(0);
    }

    // ================= A side (active while t <= qtA; block-uniform) =========
    if (t <= qtA) {
      f32x4 st[4];
      __builtin_amdgcn_s_setprio(1);
      #pragma unroll
      for (int u = 0; u < 4; ++u) {
        f32x4 z; z[0] = z[1] = z[2] = z[3] = 0.0f;
        z = mfma16(kf0[u], qfA0, z);
        z = mfma16(kf1[u], qfA1, z);
        st[u] = z;
      }
      __builtin_amdgcn_s_setprio(0);

      float pv[16];
      if (t == qtA) {
        const int kv0 = t * 64;
        #pragma unroll
        for (int u = 0; u < 4; ++u)
          #pragma unroll
          for (int r = 0; r < 4; ++r) {
            const int kv = kv0 + 16 * u + 4 * g + r;
            pv[u * 4 + r] = (kv <= qA) ? st[u][r] : -1e30f;
          }
      } else {
        #pragma unroll
        for (int u = 0; u < 4; ++u)
          #pragma unroll
          for (int r = 0; r < 4; ++r)
            pv[u * 4 + r] = st[u][r];
      }

      float ma = fmaxf(fmaxf(pv[0], pv[1]), fmaxf(pv[2], pv[3]));
      float mb = fmaxf(fmaxf(pv[4], pv[5]), fmaxf(pv[6], pv[7]));
      float mc = fmaxf(fmaxf(pv[8], pv[9]), fmaxf(pv[10], pv[11]));
      float md = fmaxf(fmaxf(pv[12], pv[13]), fmaxf(pv[14], pv[15]));
      const float lmx = fmaxf(fmaxf(ma, mb), fmaxf(mc, md));

      if (__any(lmx - mA > 12.0f)) {
        float mx = fmaxf(lmx, __shfl_xor(lmx, 16));
        mx = fmaxf(mx, __shfl_xor(mx, 32));
        const float mn = fmaxf(mA, mx);
        const float alpha = exp2f(mA - mn);
        lA *= alpha;
        #pragma unroll
        for (int dblk = 0; dblk < 4; ++dblk)
          #pragma unroll
          for (int e = 0; e < 4; ++e) oaccA[dblk][e] *= alpha;
        mA = mn;
      }

      #pragma unroll
      for (int i = 0; i < 16; ++i) pv[i] = exp2f(pv[i] - mA);
      float s0 = (pv[0] + pv[1]) + (pv[2] + pv[3]);
      float s1 = (pv[4] + pv[5]) + (pv[6] + pv[7]);
      float s2 = (pv[8] + pv[9]) + (pv[10] + pv[11]);
      float s3 = (pv[12] + pv[13]) + (pv[14] + pv[15]);
      lA += (s0 + s1) + (s2 + s3);

      bf16x8 pf0, pf1;
      #pragma unroll
      for (int j = 0; j < 8; ++j) {
        pf0[j] = (bf16_t)pv[j];
        pf1[j] = (bf16_t)pv[8 + j];
      }

      __builtin_amdgcn_s_setprio(1);
      #pragma unroll
      for (int dblk = 0; dblk < 4; ++dblk) {
        oaccA[dblk] = mfma16(vlo[dblk], pf0, oaccA[dblk]);
        oaccA[dblk] = mfma16(vhi[dblk], pf1, oaccA[dblk]);
      }
      __builtin_amdgcn_s_setprio(0);
    }

    __syncthreads();
  }

  // ---- epilogues ----
  lA += __shfl_xor(lA, 16);
  lA += __shfl_xor(lA, 32);
  lB += __shfl_xor(lB, 16);
  lB += __shfl_xor(lB, 32);
  const float invA = 1.0f / lA;
  const float invB = 1.0f / lB;
  bf16_t* orowA = O + ((size_t)(b * SEQ + qA)) * DM + h * HD;
  bf16_t* orowB = O + ((size_t)(b * SEQ + qB)) * DM + h * HD;
  #pragma unroll
  for (int dblk = 0; dblk < 4; ++dblk) {
    bf16x4 ovA, ovB;
    #pragma unroll
    for (int r = 0; r < 4; ++r) {
      ovA[r] = (bf16_t)(oaccA[dblk][r] * invA);
      ovB[r] = (bf16_t)(oaccB[dblk][r] * invB);
    }
    *(bf16x4*)&orowA[dblk * 16 + 4 * g] = ovA;
    *(bf16x4*)&orowB[dblk * 16 + 4 * g] = ovB;
  }
}

// ---------------- launch ----------------
extern "C" void kernel_launch(void* const* d_in, const int* in_sizes, int n_in,
                              void* d_out, int out_size, void* d_ws, size_t ws_size,
                              hipStream_t stream)
{
  const float* x  = (const float*)d_in[0];
  const float* Wq = (const float*)d_in[1];
  const float* bq = (const float*)d_in[2];
  const float* Wk = (const float*)d_in[3];
  const float* bk = (const float*)d_in[4];
  const float* Wv = (const float*)d_in[5];
  const float* bv = (const float*)d_in[6];
  const float* Wo = (const float*)d_in[7];
  const float* bo = (const float*)d_in[8];
  float* out = (float*)d_out;

  char* ws = (char*)d_ws;
  size_t off = 0;
  auto alloc = [&](size_t bytes) { char* p = ws + off; off += (bytes + 255) & ~255ULL; return p; };
  bf16_t* xb   = (bf16_t*)alloc((size_t)BS * DM * 2);
  bf16_t* Wcat = (bf16_t*)alloc((size_t)NQKV * DM * 2);
  bf16_t* Wob  = (bf16_t*)alloc((size_t)DM * DM * 2);
  float*  bcat = (float*)alloc((size_t)NQKV * 4);
  float2* rt   = (float2*)alloc((size_t)SEQ * 32 * 8);
  bf16_t* Qh   = (bf16_t*)alloc((size_t)BS * DM * 2);
  bf16_t* Kh   = (bf16_t*)alloc((size_t)BS * DM * 2);
  bf16_t* Vth  = (bf16_t*)alloc((size_t)BS * DM * 2);
  bf16_t* Oh   = (bf16_t*)alloc((size_t)BS * DM * 2);
  (void)ws_size; (void)in_sizes; (void)n_in; (void)out_size;

  k_cast_all<<<4099 + 256, 256, 0, stream>>>(x, Wq, Wk, Wv, Wo, bq, bk, bv,
                                             xb, Wcat, Wob, bcat, rt);

  dim3 gqk(16, 32);
  k_gemm_qk<<<gqk, 256, 0, stream>>>(xb, Wcat, bcat, rt, Qh, Kh);
  dim3 gv(8, 32);
  k_gemm_v<<<gv, 256, 0, stream>>>(xb, Wcat + 2 * DM * DM, bcat + 2 * DM, Vth);
  k_attn<<<512, 256, 0, stream>>>(Qh, Kh, Vth, Oh);
  dim3 g2(DM / 128, BS / 128);
  k_gemm_out<<<g2, 512, 0, stream>>>(Oh, Wob, bo, out);
}

// Round 22
// 113.547 us; speedup vs baseline: 1.0893x; 1.0410x over previous
//
#include <hip/hip_runtime.h>
#include <hip/hip_bf16.h>
#include <stdint.h>

typedef __bf16 bf16_t;
typedef __bf16 bf16x4 __attribute__((ext_vector_type(4)));
typedef __bf16 bf16x8 __attribute__((ext_vector_type(8)));
typedef float  f32x4  __attribute__((ext_vector_type(4)));

#define DM    1024
#define NH    16
#define HD    64
#define SEQ   2048
#define BATCH 2
#define BS    (BATCH*SEQ)   // 4096
#define NQKV  (3*DM)        // 3072

#define GLOAD_LDS16(g, l) \
  __builtin_amdgcn_global_load_lds((const __attribute__((address_space(1))) void*)(g), \
                                   (__attribute__((address_space(3))) void*)(l), 16, 0, 0)

__device__ __forceinline__ f32x4 mfma16(bf16x8 a, bf16x8 b, f32x4 c) {
  return __builtin_amdgcn_mfma_f32_16x16x32_bf16(a, b, c, 0, 0, 0);
}

// ---------------- merged cast/copy + rope-table kernel ----------------
__global__ __launch_bounds__(256) void k_cast_all(
    const float* __restrict__ x,  const float* __restrict__ Wq,
    const float* __restrict__ Wk, const float* __restrict__ Wv,
    const float* __restrict__ Wo, const float* __restrict__ bq,
    const float* __restrict__ bk, const float* __restrict__ bv,
    bf16_t* __restrict__ xb, bf16_t* __restrict__ Wcat,
    bf16_t* __restrict__ Wob, float* __restrict__ bcat,
    float2* __restrict__ rt)
{
  const int bid = blockIdx.x, tid = threadIdx.x;
  if (bid >= 4099) {
    const int idx = (bid - 4099) * 256 + tid;   // SEQ*32 = 65536 entries
    const int s = idx >> 5, i = idx & 31;
    float inv = powf(10000.0f, -(float)(2 * i) / 64.0f);
    float ang = (float)s * inv;
    rt[idx] = make_float2(cosf(ang), sinf(ang));
    return;
  }
  if (bid >= 4096) {
    const int k = bid - 4096;
    const float* src = (k == 0) ? bq : (k == 1) ? bk : bv;
    *(float4*)&bcat[k * DM + tid * 4] = *(const float4*)&src[tid * 4];
    return;
  }
  const float* src; bf16_t* dst; int i;
  if (bid < 2048)      { src = x;  dst = xb;                i = bid * 2048 + tid * 8; }
  else if (bid < 2560) { src = Wq; dst = Wcat;              i = (bid - 2048) * 2048 + tid * 8; }
  else if (bid < 3072) { src = Wk; dst = Wcat + DM * DM;    i = (bid - 2560) * 2048 + tid * 8; }
  else if (bid < 3584) { src = Wv; dst = Wcat + 2 * DM * DM;i = (bid - 3072) * 2048 + tid * 8; }
  else                 { src = Wo; dst = Wob;               i = (bid - 3584) * 2048 + tid * 8; }
  float4 a = *(const float4*)(src + i);
  float4 b = *(const float4*)(src + i + 4);
  bf16x8 o;
  o[0] = (bf16_t)a.x; o[1] = (bf16_t)a.y; o[2] = (bf16_t)a.z; o[3] = (bf16_t)a.w;
  o[4] = (bf16_t)b.x; o[5] = (bf16_t)b.y; o[6] = (bf16_t)b.z; o[7] = (bf16_t)b.w;
  *(bf16x8*)(dst + i) = o;
}

// ---------------- Q/K projection GEMM (C^T) + bias + RoPE: 8 waves, dbuf, T1 ----
// 512 threads, wave (wr=w>>2, wc=w&3) owns 64x32 of the 128x128 tile, acc[4][2].
// Swapped mfma -> C^T: acc[i][j][e] = C[m][n], n = n0+wc*32+j*16+4g+e (e-contig),
// m = m0+wr*64+i*16+c16. RoPE pairs lane-local; bf16x4 stores.
__global__ __launch_bounds__(512) void k_gemm_qk(
    const bf16_t* __restrict__ A, const bf16_t* __restrict__ B,
    const float* __restrict__ bias, const float2* __restrict__ rt,
    bf16_t* __restrict__ Qo, bf16_t* __restrict__ Ko)
{
  const int K = DM;
  __shared__ __align__(16) bf16_t As[2][128 * 32];
  __shared__ __align__(16) bf16_t Bs[2][128 * 32];
  const int tid  = threadIdx.x;
  const int lane = tid & 63;
  const int w    = tid >> 6;
  const int wr = w >> 2, wc = w & 3;
  // T1 XCD swizzle: nwg=512, bijective
  const int orig = blockIdx.y * 16 + blockIdx.x;
  const int wid  = (orig & 7) * 64 + (orig >> 3);
  const int m0 = (wid >> 4) * 128, n0 = (wid & 15) * 128;
  const int c16 = lane & 15, g = lane >> 4;

  f32x4 acc[4][2];
  #pragma unroll
  for (int i = 0; i < 4; ++i)
    #pragma unroll
    for (int j = 0; j < 2; ++j)
      #pragma unroll
      for (int e = 0; e < 4; ++e) acc[i][j][e] = 0.0f;

  const int lrow = lane >> 2;
  const int lk   = (lane & 3) * 8;
  const bf16_t* ga = A + (size_t)(m0 + w * 16 + lrow) * K + lk;
  const bf16_t* gb = B + (size_t)(n0 + w * 16 + lrow) * K + lk;
  bf16_t* laA = &As[0][(w * 16) * 32]; bf16_t* laB = &As[1][(w * 16) * 32];
  bf16_t* lbA = &Bs[0][(w * 16) * 32]; bf16_t* lbB = &Bs[1][(w * 16) * 32];

  const int po = (wr * 64 + c16) * 32 + g * 8;
  const int qo = (wc * 32 + c16) * 32 + g * 8;
  const bf16_t* paA = &As[0][po]; const bf16_t* paB = &As[1][po];
  const bf16_t* pbA = &Bs[0][qo]; const bf16_t* pbB = &Bs[1][qo];

  GLOAD_LDS16(ga, laA); GLOAD_LDS16(gb, lbA);
  __syncthreads();

  for (int it = 0; it < K / 32; ++it) {
    const bool odd = it & 1;
    const int kt = it * 32;
    if (kt + 32 < K) {
      GLOAD_LDS16(ga + kt + 32, odd ? laA : laB);
      GLOAD_LDS16(gb + kt + 32, odd ? lbA : lbB);
    }
    const bf16_t* pa = odd ? paB : paA;
    const bf16_t* pb = odd ? pbB : pbA;
    bf16x8 af[4], bfr[2];
    #pragma unroll
    for (int t = 0; t < 4; ++t) af[t]  = *(const bf16x8*)(pa + t * 16 * 32);
    #pragma unroll
    for (int t = 0; t < 2; ++t) bfr[t] = *(const bf16x8*)(pb + t * 16 * 32);
    #pragma unroll
    for (int i = 0; i < 4; ++i)
      #pragma unroll
      for (int j = 0; j < 2; ++j)
        acc[i][j] = mfma16(bfr[j], af[i], acc[i][j]);   // SWAPPED -> C^T layout
    __syncthreads();
  }

  const int region = n0 >> 10;                 // 0=Q, 1=K
  bf16_t* dst = region ? Ko : Qo;
  const float qs = region ? 1.0f : (0.125f * 1.44269504088896f);
  #pragma unroll
  for (int j = 0; j < 2; ++j) {
    const int nb = n0 + wc * 32 + j * 16 + (g << 2);   // n of e=0
    const float4 bv = *(const float4*)&bias[nb];
    const int h  = (nb >> 6) & 15;
    const int d0 = nb & 63;
    #pragma unroll
    for (int i = 0; i < 4; ++i) {
      const int m = m0 + wr * 64 + i * 16 + c16;
      const int s = m & 2047;
      const int bh = ((m >> 11) << 4) + h;
      const float4 cs = *(const float4*)&rt[(size_t)s * 32 + (d0 >> 1)];
      const float v0 = acc[i][j][0] + bv.x;
      const float v1 = acc[i][j][1] + bv.y;
      const float v2 = acc[i][j][2] + bv.z;
      const float v3 = acc[i][j][3] + bv.w;
      bf16x4 ov;
      ov[0] = (bf16_t)((v0 * cs.x - v1 * cs.y) * qs);
      ov[1] = (bf16_t)((v0 * cs.y + v1 * cs.x) * qs);
      ov[2] = (bf16_t)((v2 * cs.z - v3 * cs.w) * qs);
      ov[3] = (bf16_t)((v2 * cs.w + v3 * cs.z) * qs);
      *(bf16x4*)&dst[((size_t)bh * SEQ + s) * HD + d0] = ov;
    }
  }
}

// ---------------- V projection GEMM + bias + PERMUTED V^T: 8 waves, dbuf, T1 ----
__global__ __launch_bounds__(512) void k_gemm_v(
    const bf16_t* __restrict__ A, const bf16_t* __restrict__ B,
    const float* __restrict__ bias, bf16_t* __restrict__ Vt)
{
  const int K = DM;
  __shared__ __align__(16) bf16_t As[2][128 * 32];
  __shared__ __align__(16) bf16_t Bs[2][128 * 32];
  const int tid  = threadIdx.x;
  const int lane = tid & 63;
  const int w    = tid >> 6;
  const int wr = w >> 2, wc = w & 3;
  // T1 XCD swizzle: nwg=256
  const int orig = blockIdx.y * 8 + blockIdx.x;
  const int wid  = (orig & 7) * 32 + (orig >> 3);
  const int m0 = (wid >> 3) * 128, n0 = (wid & 7) * 128;
  const int c16 = lane & 15, g = lane >> 4;

  f32x4 acc[4][2];
  #pragma unroll
  for (int i = 0; i < 4; ++i)
    #pragma unroll
    for (int j = 0; j < 2; ++j)
      #pragma unroll
      for (int e = 0; e < 4; ++e) acc[i][j][e] = 0.0f;

  const int lrow = lane >> 2;
  const int lk   = (lane & 3) * 8;
  const bf16_t* ga = A + (size_t)(m0 + w * 16 + lrow) * K + lk;
  const bf16_t* gb = B + (size_t)(n0 + w * 16 + lrow) * K + lk;
  bf16_t* laA = &As[0][(w * 16) * 32]; bf16_t* laB = &As[1][(w * 16) * 32];
  bf16_t* lbA = &Bs[0][(w * 16) * 32]; bf16_t* lbB = &Bs[1][(w * 16) * 32];

  const int po = (wr * 64 + c16) * 32 + g * 8;
  const int qo = (wc * 32 + c16) * 32 + g * 8;
  const bf16_t* paA = &As[0][po]; const bf16_t* paB = &As[1][po];
  const bf16_t* pbA = &Bs[0][qo]; const bf16_t* pbB = &Bs[1][qo];

  GLOAD_LDS16(ga, laA); GLOAD_LDS16(gb, lbA);
  __syncthreads();

  for (int it = 0; it < K / 32; ++it) {
    const bool odd = it & 1;
    const int kt = it * 32;
    if (kt + 32 < K) {
      GLOAD_LDS16(ga + kt + 32, odd ? laA : laB);
      GLOAD_LDS16(gb + kt + 32, odd ? lbA : lbB);
    }
    const bf16_t* pa = odd ? paB : paA;
    const bf16_t* pb = odd ? pbB : pbA;
    bf16x8 af[4], bfr[2];
    #pragma unroll
    for (int t = 0; t < 4; ++t) af[t]  = *(const bf16x8*)(pa + t * 16 * 32);
    #pragma unroll
    for (int t = 0; t < 2; ++t) bfr[t] = *(const bf16x8*)(pb + t * 16 * 32);
    #pragma unroll
    for (int i = 0; i < 4; ++i)
      #pragma unroll
      for (int j = 0; j < 2; ++j)
        acc[i][j] = mfma16(af[i], bfr[j], acc[i][j]);
    __syncthreads();
  }

  const int rbase = m0 + wr * 64 + (g << 2);
  const int cbase = n0 + wc * 32 + c16;
  #pragma unroll
  for (int j = 0; j < 2; ++j) {
    const int c = cbase + j * 16;
    const float bv = bias[c];
    const int h = (c >> 6) & 15;
    const int d = c & 63;
    #pragma unroll
    for (int i = 0; i < 4; ++i) {
      bf16x4 ov;
      #pragma unroll
      for (int e = 0; e < 4; ++e) ov[e] = (bf16_t)(acc[i][j][e] + bv);
      const int r0 = rbase + i * 16;
      const int bh = ((r0 >> 11) << 4) + h;
      const int s0 = r0 & 2047;
      const int u  = (s0 >> 4) & 3;
      const int p0 = (s0 & ~63) + ((u >> 1) << 5) + (g << 3) + ((u & 1) << 2);
      *(bf16x4*)&Vt[((size_t)bh * HD + d) * SEQ + p0] = ov;
    }
  }
}

// ---------------- output projection GEMM: 8 waves, dbuf + XCD swizzle -----------
__global__ __launch_bounds__(512) void k_gemm_out(
    const bf16_t* __restrict__ A, const bf16_t* __restrict__ B,
    const float* __restrict__ bias, float* __restrict__ C)
{
  const int K = DM, N = DM;
  __shared__ __align__(16) bf16_t As[2][128 * 32];
  __shared__ __align__(16) bf16_t Bs[2][128 * 32];
  const int tid  = threadIdx.x;
  const int lane = tid & 63;
  const int w    = tid >> 6;
  const int wr = w >> 2, wc = w & 3;
  // T1 XCD swizzle: nwg=256
  const int orig = blockIdx.y * 8 + blockIdx.x;
  const int wid  = (orig & 7) * 32 + (orig >> 3);
  const int m0 = (wid >> 3) * 128, n0 = (wid & 7) * 128;
  const int c16 = lane & 15, g = lane >> 4;

  f32x4 acc[4][2];
  #pragma unroll
  for (int i = 0; i < 4; ++i)
    #pragma unroll
    for (int j = 0; j < 2; ++j)
      #pragma unroll
      for (int e = 0; e < 4; ++e) acc[i][j][e] = 0.0f;

  const int lrow = lane >> 2;
  const int lk   = (lane & 3) * 8;
  const bf16_t* ga = A + (size_t)(m0 + w * 16 + lrow) * K + lk;
  const bf16_t* gb = B + (size_t)(n0 + w * 16 + lrow) * K + lk;
  bf16_t* laA = &As[0][(w * 16) * 32]; bf16_t* laB = &As[1][(w * 16) * 32];
  bf16_t* lbA = &Bs[0][(w * 16) * 32]; bf16_t* lbB = &Bs[1][(w * 16) * 32];

  const int po = (wr * 64 + c16) * 32 + g * 8;
  const int qo = (wc * 32 + c16) * 32 + g * 8;
  const bf16_t* paA = &As[0][po]; const bf16_t* paB = &As[1][po];
  const bf16_t* pbA = &Bs[0][qo]; const bf16_t* pbB = &Bs[1][qo];

  GLOAD_LDS16(ga, laA); GLOAD_LDS16(gb, lbA);
  __syncthreads();

  for (int it = 0; it < K / 32; ++it) {
    const bool odd = it & 1;
    const int kt = it * 32;
    if (kt + 32 < K) {
      GLOAD_LDS16(ga + kt + 32, odd ? laA : laB);
      GLOAD_LDS16(gb + kt + 32, odd ? lbA : lbB);
    }
    const bf16_t* pa = odd ? paB : paA;
    const bf16_t* pb = odd ? pbB : pbA;
    bf16x8 af[4], bfr[2];
    #pragma unroll
    for (int t = 0; t < 4; ++t) af[t]  = *(const bf16x8*)(pa + t * 16 * 32);
    #pragma unroll
    for (int t = 0; t < 2; ++t) bfr[t] = *(const bf16x8*)(pb + t * 16 * 32);
    #pragma unroll
    for (int i = 0; i < 4; ++i)
      #pragma unroll
      for (int j = 0; j < 2; ++j)
        acc[i][j] = mfma16(af[i], bfr[j], acc[i][j]);
    __syncthreads();
  }

  const int rbase = m0 + wr * 64 + (g << 2);
  const int cbase = n0 + wc * 32 + c16;
  #pragma unroll
  for (int j = 0; j < 2; ++j) {
    const int c = cbase + j * 16;
    const float bv = bias[c];
    #pragma unroll
    for (int i = 0; i < 4; ++i) {
      #pragma unroll
      for (int e = 0; e < 4; ++e) {
        const int r = rbase + i * 16 + e;
        C[(size_t)r * N + c] = acc[i][j][e] + bv;
      }
    }
  }
}

// ---------------- flash attention: fused diagonal-pair (r19/r21 best: 42.6 us) ---
__global__ __launch_bounds__(256, 2) void k_attn(
    const bf16_t* __restrict__ Q, const bf16_t* __restrict__ K,
    const bf16_t* __restrict__ Vt, bf16_t* __restrict__ O)
{
  __shared__ __align__(16) bf16_t kbuf[2][64 * 64];
  __shared__ __align__(16) bf16_t vbuf[2][64 * 64];
  const int tid = threadIdx.x, lane = tid & 63, w = tid >> 6;
  const int pr = blockIdx.x >> 5;          // 0..15
  const int bh = blockIdx.x & 31;
  const int b  = bh >> 4, h = bh & 15;
  const int c16 = lane & 15;
  const int g   = lane >> 4;

  const bf16_t* Qb = Q  + (size_t)bh * SEQ * HD;
  const bf16_t* Kb = K  + (size_t)bh * SEQ * HD;
  const bf16_t* Vb = Vt + (size_t)bh * HD * SEQ;

  const int qtA = pr, qtB = 31 - pr;
  const int qA  = qtA * 64 + w * 16 + c16;
  const int qB  = qtB * 64 + w * 16 + c16;
  const int Tmax = qtB + 1;                // 32 - pr staged tiles

  bf16x8 qfA0 = *(const bf16x8*)&Qb[(size_t)qA * HD + g * 8];
  bf16x8 qfA1 = *(const bf16x8*)&Qb[(size_t)qA * HD + 32 + g * 8];
  bf16x8 qfB0 = *(const bf16x8*)&Qb[(size_t)qB * HD + g * 8];
  bf16x8 qfB1 = *(const bf16x8*)&Qb[(size_t)qB * HD + 32 + g * 8];

  f32x4 oaccA[4], oaccB[4];
  #pragma unroll
  for (int dblk = 0; dblk < 4; ++dblk)
    #pragma unroll
    for (int e = 0; e < 4; ++e) { oaccA[dblk][e] = 0.0f; oaccB[dblk][e] = 0.0f; }
  float mA = -1e30f, lA = 0.0f, mB = -1e30f, lB = 0.0f;

  const int soff0 = w * 1024 + lane * 16;
  const int soff1 = soff0 + 4096;
  const int srow0 = soff0 >> 7, srow1 = soff1 >> 7;
  const int scb0  = (soff0 & 127) ^ ((srow0 & 7) << 4);
  const int scb1  = (soff1 & 127) ^ ((srow1 & 7) << 4);
  const bf16_t* gk0 = &Kb[(size_t)srow0 * HD + (scb0 >> 1)];
  const bf16_t* gk1 = &Kb[(size_t)srow1 * HD + (scb1 >> 1)];
  const bf16_t* gv0 = &Vb[(size_t)srow0 * SEQ + (scb0 >> 1)];
  const bf16_t* gv1 = &Vb[(size_t)srow1 * SEQ + (scb1 >> 1)];
  bf16_t* lk0A = &kbuf[0][(w * 1024) >> 1];
  bf16_t* lk1A = &kbuf[0][(w * 1024 + 4096) >> 1];
  bf16_t* lk0B = &kbuf[1][(w * 1024) >> 1];
  bf16_t* lk1B = &kbuf[1][(w * 1024 + 4096) >> 1];
  bf16_t* lv0A = &vbuf[0][(w * 1024) >> 1];
  bf16_t* lv1A = &vbuf[0][(w * 1024 + 4096) >> 1];
  bf16_t* lv0B = &vbuf[1][(w * 1024) >> 1];
  bf16_t* lv1B = &vbuf[1][(w * 1024 + 4096) >> 1];

  const int sw = (c16 & 7) << 4;
  const int e0 = ((16 * g) ^ sw) >> 1;
  const int dhi = (((64 + 16 * g) ^ sw) >> 1) - e0;
  const bf16_t* kp0 = &kbuf[0][c16 * 64 + e0];
  const bf16_t* kp1 = &kbuf[1][c16 * 64 + e0];
  const bf16_t* vp0 = &vbuf[0][c16 * 64 + e0];
  const bf16_t* vp1 = &vbuf[1][c16 * 64 + e0];

  GLOAD_LDS16(gk0, lk0A); GLOAD_LDS16(gk1, lk1A);
  GLOAD_LDS16(gv0, lv0A); GLOAD_LDS16(gv1, lv1A);
  gk0 += 4096; gk1 += 4096; gv0 += 64; gv1 += 64;
  __syncthreads();

  for (int t = 0; t < Tmax; ++t) {
    const bool odd = t & 1;
    if (t + 1 < Tmax) {
      GLOAD_LDS16(gk0, odd ? lk0A : lk0B); GLOAD_LDS16(gk1, odd ? lk1A : lk1B);
      GLOAD_LDS16(gv0, odd ? lv0A : lv0B); GLOAD_LDS16(gv1, odd ? lv1A : lv1B);
      gk0 += 4096; gk1 += 4096; gv0 += 64; gv1 += 64;
    }

    const bf16_t* kp = odd ? kp1 : kp0;
    const bf16_t* vp = odd ? vp1 : vp0;

    // ---- HOISTED fragment loads: 16 ds_read_b128, shared by A and B sides ----
    bf16x8 kf0[4], kf1[4], vlo[4], vhi[4];
    #pragma unroll
    for (int u = 0; u < 4; ++u) {
      kf0[u] = *(const bf16x8*)(kp + u * 1024);
      kf1[u] = *(const bf16x8*)(kp + u * 1024 + dhi);
    }
    #pragma unroll
    for (int dblk = 0; dblk < 4; ++dblk) {
      vlo[dblk] = *(const bf16x8*)(vp + dblk * 1024);
      vhi[dblk] = *(const bf16x8*)(vp + dblk * 1024 + dhi);
    }

    // ================= B side (always active) =================
    {
      f32x4 st[4];
      __builtin_amdgcn_s_setprio(1);
      #pragma unroll
      for (int u = 0; u < 4; ++u) {
        f32x4 z; z[0] = z[1] = z[2] = z[3] = 0.0f;
        z = mfma16(kf0[u], qfB0, z);
        z = mfma16(kf1[u], qfB1, z);
        st[u] = z;
      }
      __builtin_amdgcn_s_setprio(0);

      float pv[16];
      if (t == qtB) {
        const int kv0 = t * 64;
        #pragma unroll
        for (int u = 0; u < 4; ++u)
          #pragma unroll
          for (int r = 0; r < 4; ++r) {
            const int kv = kv0 + 16 * u + 4 * g + r;
            pv[u * 4 + r] = (kv <= qB) ? st[u][r] : -1e30f;
          }
      } else {
        #pragma unroll
        for (int u = 0; u < 4; ++u)
          #pragma unroll
          for (int r = 0; r < 4; ++r)
            pv[u * 4 + r] = st[u][r];
      }

      float ma = fmaxf(fmaxf(pv[0], pv[1]), fmaxf(pv[2], pv[3]));
      float mb = fmaxf(fmaxf(pv[4], pv[5]), fmaxf(pv[6], pv[7]));
      float mc = fmaxf(fmaxf(pv[8], pv[9]), fmaxf(pv[10], pv[11]));
      float md = fmaxf(fmaxf(pv[12], pv[13]), fmaxf(pv[14], pv[15]));
      const float lmx = fmaxf(fmaxf(ma, mb), fmaxf(mc, md));

      if (__any(lmx - mB > 12.0f)) {
        float mx = fmaxf(lmx, __shfl_xor(lmx, 16));
        mx = fmaxf(mx, __shfl_xor(mx, 32));
        const float mn = fmaxf(mB, mx);
        const float alpha = exp2f(mB - mn);
        lB *= alpha;
        #pragma unroll
        for (int dblk = 0; dblk < 4; ++dblk)
          #pragma unroll
          for (int e = 0; e < 4; ++e) oaccB[dblk][e] *= alpha;
        mB = mn;
      }

      #pragma unroll
      for (int i = 0; i < 16; ++i) pv[i] = exp2f(pv[i] - mB);
      float s0 = (pv[0] + pv[1]) + (pv[2] + pv[3]);
      float s1 = (pv[4] + pv[5]) + (pv[6] + pv[7]);
      float s2 = (pv[8] + pv[9]) + (pv[10] + pv[11]);
      float s3 = (pv[12] + pv[13]) + (pv[14] + pv[15]);
      lB += (s0 + s1) + (s2 + s3);

      bf16x8 pf0, pf1;
      #pragma unroll
      for (int j = 0; j < 8; ++j) {
        pf0[j] = (bf16_t)pv[j];
        pf1[j] = (bf16_t)pv[8 + j];
      }

      __builtin_amdgcn_s_setprio(1);
      #pragma unroll
      for (int dblk = 0; dblk < 4; ++dblk) {
        oaccB[dblk] = mfma16(vlo[dblk], pf0, oaccB[dblk]);
        oaccB[dblk] = mfma16(vhi[dblk], pf1, oaccB[dblk]);
      }
      __builtin_amdgcn_s_setprio(0);
    }

    // ================= A side (active while t <= qtA; block-uniform) =========
    if (t <= qtA) {
      f32x4 st[4];
      __builtin_amdgcn_s_setprio(1);
      #pragma unroll
      for (int u = 0; u < 4; ++u) {
        f32x4 z; z[0] = z[1] = z[2] = z[3] = 0.0f;
        z = mfma16(kf0[u], qfA0, z);
        z = mfma16(kf1[u], qfA1, z);
        st[u] = z;
      }
      __builtin_amdgcn_s_setprio(0);

      float pv[16];
      if (t == qtA) {
        const int kv0 = t * 64;
        #pragma unroll
        for (int u = 0; u < 4; ++u)
          #pragma unroll
          for (int r = 0; r < 4; ++r) {
            const int kv = kv0 + 16 * u + 4 * g + r;
            pv[u * 4 + r] = (kv <= qA) ? st[u][r] : -1e30f;
          }
      } else {
        #pragma unroll
        for (int u = 0; u < 4; ++u)
          #pragma unroll
          for (int r = 0; r < 4; ++r)
            pv[u * 4 + r] = st[u][r];
      }

      float ma = fmaxf(fmaxf(pv[0], pv[1]), fmaxf(pv[2], pv[3]));
      float mb = fmaxf(fmaxf(pv[4], pv[5]), fmaxf(pv[6], pv[7]));
      float mc = fmaxf(fmaxf(pv[8], pv[9]), fmaxf(pv[10], pv[11]));
      float md = fmaxf(fmaxf(pv[12], pv[13]), fmaxf(pv[14], pv[15]));
      const float lmx = fmaxf(fmaxf(ma, mb), fmaxf(mc, md));

      if (__any(lmx - mA > 12.0f)) {
        float mx = fmaxf(lmx, __shfl_xor(lmx, 16));
        mx = fmaxf(mx, __shfl_xor(mx, 32));
        const float mn = fmaxf(mA, mx);
        const float alpha = exp2f(mA - mn);
        lA *= alpha;
        #pragma unroll
        for (int dblk = 0; dblk < 4; ++dblk)
          #pragma unroll
          for (int e = 0; e < 4; ++e) oaccA[dblk][e] *= alpha;
        mA = mn;
      }

      #pragma unroll
      for (int i = 0; i < 16; ++i) pv[i] = exp2f(pv[i] - mA);
      float s0 = (pv[0] + pv[1]) + (pv[2] + pv[3]);
      float s1 = (pv[4] + pv[5]) + (pv[6] + pv[7]);
      float s2 = (pv[8] + pv[9]) + (pv[10] + pv[11]);
      float s3 = (pv[12] + pv[13]) + (pv[14] + pv[15]);
      lA += (s0 + s1) + (s2 + s3);

      bf16x8 pf0, pf1;
      #pragma unroll
      for (int j = 0; j < 8; ++j) {
        pf0[j] = (bf16_t)pv[j];
        pf1[j] = (bf16_t)pv[8 + j];
      }

      __builtin_amdgcn_s_setprio(1);
      #pragma unroll
      for (int dblk = 0; dblk < 4; ++dblk) {
        oaccA[dblk] = mfma16(vlo[dblk], pf0, oaccA[dblk]);
        oaccA[dblk] = mfma16(vhi[dblk], pf1, oaccA[dblk]);
      }
      __builtin_amdgcn_s_setprio(0);
    }

    __syncthreads();
  }

  // ---- epilogues ----
  lA += __shfl_xor(lA, 16);
  lA += __shfl_xor(lA, 32);
  lB += __shfl_xor(lB, 16);
  lB += __shfl_xor(lB, 32);
  const float invA = 1.0f / lA;
  const float invB = 1.0f / lB;
  bf16_t* orowA = O + ((size_t)(b * SEQ + qA)) * DM + h * HD;
  bf16_t* orowB = O + ((size_t)(b * SEQ + qB)) * DM + h * HD;
  #pragma unroll
  for (int dblk = 0; dblk < 4; ++dblk) {
    bf16x4 ovA, ovB;
    #pragma unroll
    for (int r = 0; r < 4; ++r) {
      ovA[r] = (bf16_t)(oaccA[dblk][r] * invA);
      ovB[r] = (bf16_t)(oaccB[dblk][r] * invB);
    }
    *(bf16x4*)&orowA[dblk * 16 + 4 * g] = ovA;
    *(bf16x4*)&orowB[dblk * 16 + 4 * g] = ovB;
  }
}

// ---------------- launch ----------------
extern "C" void kernel_launch(void* const* d_in, const int* in_sizes, int n_in,
                              void* d_out, int out_size, void* d_ws, size_t ws_size,
                              hipStream_t stream)
{
  const float* x  = (const float*)d_in[0];
  const float* Wq = (const float*)d_in[1];
  const float* bq = (const float*)d_in[2];
  const float* Wk = (const float*)d_in[3];
  const float* bk = (const float*)d_in[4];
  const float* Wv = (const float*)d_in[5];
  const float* bv = (const float*)d_in[6];
  const float* Wo = (const float*)d_in[7];
  const float* bo = (const float*)d_in[8];
  float* out = (float*)d_out;

  char* ws = (char*)d_ws;
  size_t off = 0;
  auto alloc = [&](size_t bytes) { char* p = ws + off; off += (bytes + 255) & ~255ULL; return p; };
  bf16_t* xb   = (bf16_t*)alloc((size_t)BS * DM * 2);
  bf16_t* Wcat = (bf16_t*)alloc((size_t)NQKV * DM * 2);
  bf16_t* Wob  = (bf16_t*)alloc((size_t)DM * DM * 2);
  float*  bcat = (float*)alloc((size_t)NQKV * 4);
  float2* rt   = (float2*)alloc((size_t)SEQ * 32 * 8);
  bf16_t* Qh   = (bf16_t*)alloc((size_t)BS * DM * 2);
  bf16_t* Kh   = (bf16_t*)alloc((size_t)BS * DM * 2);
  bf16_t* Vth  = (bf16_t*)alloc((size_t)BS * DM * 2);
  bf16_t* Oh   = (bf16_t*)alloc((size_t)BS * DM * 2);
  (void)ws_size; (void)in_sizes; (void)n_in; (void)out_size;

  k_cast_all<<<4099 + 256, 256, 0, stream>>>(x, Wq, Wk, Wv, Wo, bq, bk, bv,
                                             xb, Wcat, Wob, bcat, rt);

  dim3 gqk(16, 32);
  k_gemm_qk<<<gqk, 512, 0, stream>>>(xb, Wcat, bcat, rt, Qh, Kh);
  dim3 gv(8, 32);
  k_gemm_v<<<gv, 512, 0, stream>>>(xb, Wcat + 2 * DM * DM, bcat + 2 * DM, Vth);
  k_attn<<<512, 256, 0, stream>>>(Qh, Kh, Vth, Oh);
  dim3 g2(DM / 128, BS / 128);
  k_gemm_out<<<g2, 512, 0, stream>>>(Oh, Wob, bo, out);
}